// Round 5
// baseline (180.571 us; speedup 1.0000x reference)
//
#include <hip/hip_runtime.h>

#define B_TOTAL 16384
#define F_DIM 512
#define H_DIM 256
#define E_NUM 8
#define OUT_COLS 32
#define DA 8
#define TM 32
#define XSTRIDE 584   // halves; 1168B rows: 16B-aligned, 8-row bank cycle
#define HSTRIDE 280   // halves; 560B rows: 16B-aligned, 8-row bank cycle

typedef __attribute__((ext_vector_type(8))) _Float16 half8;
typedef __attribute__((ext_vector_type(4))) _Float16 half4;
typedef __attribute__((ext_vector_type(4))) float float4v;

// ================= K1: deterministic scatter (blocks 0..63) + weight prep =================
// No atomics, no memset. Block j<64 re-reads act[0..j*256) to build its per-expert
// prefix (<=16K ints, ~1us), ballot-ranks its own chunk, scatters idxbuf. Block 63
// writes counts[]. Blocks 64.. transpose W1/W2 to (E,H,K) fp16 and pack W3.
// Prep task -> expert mapping keeps (bid & 7) == e so weights land in XCD e's L2.
__global__ __launch_bounds__(256) void k_prep(
    const float* __restrict__ W1, const float* __restrict__ W2,
    const float* __restrict__ W3, const int* __restrict__ act,
    _Float16* __restrict__ W1t, _Float16* __restrict__ W2t, _Float16* __restrict__ W3t,
    int* __restrict__ idxbuf, int* __restrict__ counts)
{
  __shared__ float tile[32][33];
  __shared__ int wavecnt[4][E_NUM];
  __shared__ int wavepre[4][E_NUM];
  __shared__ int pre[E_NUM];

  int bid = blockIdx.x;
  int t = threadIdx.x;
  int lane = t & 63, wave = t >> 6;

  if (bid < 64) {
    // ---- prefix over earlier chunks ----
    int pcnt[E_NUM];
#pragma unroll
    for (int e = 0; e < E_NUM; ++e) pcnt[e] = 0;
    for (int c = wave; c < bid; c += 4) {
#pragma unroll
      for (int s = 0; s < 4; ++s) {
        int v = act[c * 256 + s * 64 + lane] & 7;
#pragma unroll
        for (int e = 0; e < E_NUM; ++e) {
          unsigned long long m = __ballot(v == e);
          pcnt[e] += (int)__popcll(m);
        }
      }
    }
    if (lane == 0)
#pragma unroll
      for (int e = 0; e < E_NUM; ++e) wavepre[wave][e] = pcnt[e];

    // ---- own chunk: ballot ranks ----
    int myB = bid * 256 + t;
    int myE = act[myB] & 7;
    unsigned long long mymask = 0;
#pragma unroll
    for (int v = 0; v < E_NUM; ++v) {
      unsigned long long m = __ballot(myE == v);
      if (lane == 0) wavecnt[wave][v] = (int)__popcll(m);
      if (myE == v) mymask = m;
    }
    int rank = (int)__popcll(mymask & ((1ull << lane) - 1ull));
    __syncthreads();
    if (t < E_NUM)
      pre[t] = wavepre[0][t] + wavepre[1][t] + wavepre[2][t] + wavepre[3][t];
    __syncthreads();
    int woff = 0;
#pragma unroll
    for (int w = 0; w < 3; ++w)
      if (w < wave) woff += wavecnt[w][myE];
    idxbuf[myE * B_TOTAL + pre[myE] + woff + rank] = myB;
    if (bid == 63 && t < E_NUM)
      counts[t] = pre[t] + wavecnt[0][t] + wavecnt[1][t] + wavecnt[2][t] + wavecnt[3][t];
    return;
  }

  // ---- weight prep: task = bid-64; e = task&7 (XCD-aligned); sub = task>>3 ----
  int task = bid - 64;
  int e = task & 7;
  int sub = task >> 3;   // 0..127 W1 tile, 128..191 W2 tile, 192 W3 pack
  int tx = t & 31, ty = t >> 5;

  if (sub < 192) {
    const float* S; _Float16* D; int K, N, k0, n0;
    if (sub < 128) {
      K = F_DIM; N = H_DIM; k0 = (sub >> 3) * 32; n0 = (sub & 7) * 32;
      S = W1 + (size_t)e * F_DIM * H_DIM;
      D = W1t + (size_t)e * H_DIM * F_DIM;
    } else {
      int s2 = sub - 128;
      K = H_DIM; N = H_DIM; k0 = (s2 >> 3) * 32; n0 = (s2 & 7) * 32;
      S = W2 + (size_t)e * H_DIM * H_DIM;
      D = W2t + (size_t)e * H_DIM * H_DIM;
    }
#pragma unroll
    for (int r = 0; r < 32; r += 8)
      tile[ty + r][tx] = S[(size_t)(k0 + ty + r) * N + (n0 + tx)];
    __syncthreads();
#pragma unroll
    for (int r = 0; r < 32; r += 8)
      D[(size_t)(n0 + ty + r) * K + (k0 + tx)] = (_Float16)tile[tx][ty + r];
  } else {
    int k = t;
#pragma unroll
    for (int o = 0; o < 16; ++o) {
      float v = (o < DA) ? W3[((size_t)e * H_DIM + k) * OUT_COLS + o] : 0.f;
      W3t[((size_t)e * 16 + o) * H_DIM + k] = (_Float16)v;
    }
  }
}

// ================= K2: fused 3-layer MLP, XCD-pinned experts =================
// Block b: expert e = b&7 (-> XCD e), worker w = b>>3 of 64. Each task: stage 32
// gathered fp32 X rows -> fp16 LDS (16 independent float4 loads/thread), then
// L1/L2 MFMA with depth-2 global weight prefetch (weights stay in own-XCD L2).
__global__ __launch_bounds__(256, 2) void k_mlp(
    const float* __restrict__ X,
    const _Float16* __restrict__ W1t,
    const _Float16* __restrict__ W2t,
    const _Float16* __restrict__ W3t,
    const float* __restrict__ b1,
    const float* __restrict__ b2,
    const float* __restrict__ b3,
    const int* __restrict__ counts,
    const int* __restrict__ idxbuf,
    float* __restrict__ out)
{
  int e = blockIdx.x & 7;
  int worker = blockIdx.x >> 3;
  int cnt = counts[e];
  if (cnt <= 0) return;
  int ntile = (cnt + TM - 1) / TM;

  __shared__ _Float16 Xls[TM][XSTRIDE];
  __shared__ _Float16 H1s[TM][HSTRIDE];
  __shared__ int idxg[TM];
  _Float16 (*H2s)[HSTRIDE] = (_Float16(*)[HSTRIDE])&Xls[0][0];  // overlay: X dead by then

  int t = threadIdx.x;
  int lane = t & 63;
  int wave = t >> 6;
  int quad = lane >> 4;
  int l16 = lane & 15;
  int kq = quad * 8;
  int hbase = wave * 64;
  const float4v vzero = {0.f, 0.f, 0.f, 0.f};

  for (int tile = worker; tile < ntile; tile += 64) {
    int tile0 = tile * TM;
    __syncthreads();  // previous task's LDS readers done
    if (t < TM) {
      int si = tile0 + t;
      idxg[t] = idxbuf[e * B_TOTAL + (si < cnt ? si : cnt - 1)];
    }
    __syncthreads();

    // ---- stage 32x512 fp32 rows -> fp16 LDS; 16 independent 16B loads/thread ----
#pragma unroll
    for (int i = 0; i < 16; ++i) {
      int c = i * 256 + t;
      int row = c >> 7;
      int col = (c & 127) * 4;
      const float* src = X + (size_t)idxg[row] * F_DIM + col;
      float4v x = *(const float4v*)src;
      half4 h;
      h[0] = (_Float16)x.x; h[1] = (_Float16)x.y;
      h[2] = (_Float16)x.z; h[3] = (_Float16)x.w;
      *(half4*)&Xls[row][col] = h;
    }
    __syncthreads();

    float4v acc[4][2];
#pragma unroll
    for (int mt = 0; mt < 4; ++mt)
#pragma unroll
      for (int st = 0; st < 2; ++st) acc[mt][st] = vzero;

    // ======== Layer 1: A = W1t rows (depth-2 global prefetch), B = Xls ========
    {
      const _Float16* wb = W1t + ((size_t)e * H_DIM + hbase + l16) * F_DIM + kq;
      half8 a_p[2][4];
#pragma unroll
      for (int p = 0; p < 2; ++p)
#pragma unroll
        for (int mt = 0; mt < 4; ++mt)
          a_p[p][mt] = *(const half8*)(wb + (size_t)mt * 16 * F_DIM + p * 32);
#pragma unroll
      for (int kb = 0; kb < F_DIM; kb += 32) {
        int p = (kb >> 5) & 1;
        half8 a_cur[4];
#pragma unroll
        for (int mt = 0; mt < 4; ++mt) a_cur[mt] = a_p[p][mt];
        if (kb + 64 < F_DIM) {
#pragma unroll
          for (int mt = 0; mt < 4; ++mt)
            a_p[p][mt] = *(const half8*)(wb + (size_t)mt * 16 * F_DIM + kb + 64);
        }
        half8 b_cur[2];
#pragma unroll
        for (int st = 0; st < 2; ++st)
          b_cur[st] = *(const half8*)&Xls[st * 16 + l16][kb + kq];
#pragma unroll
        for (int mt = 0; mt < 4; ++mt)
#pragma unroll
          for (int st = 0; st < 2; ++st)
            acc[mt][st] = __builtin_amdgcn_mfma_f32_16x16x32_f16(a_cur[mt], b_cur[st], acc[mt][st], 0, 0, 0);
      }
#pragma unroll
      for (int mt = 0; mt < 4; ++mt) {
        int h0 = hbase + mt * 16 + quad * 4;
        float4v bb = *(const float4v*)&b1[e * H_DIM + h0];
#pragma unroll
        for (int st = 0; st < 2; ++st) {
          half4 hv;
#pragma unroll
          for (int r = 0; r < 4; ++r) {
            float v = acc[mt][st][r] + bb[r];
            hv[r] = (_Float16)(v > 0.f ? v : 0.f);
          }
          *(half4*)&H1s[st * 16 + l16][h0] = hv;
        }
      }
    }
    __syncthreads();

    // ======== Layer 2: A = W2t (prefetch), B = H1s; out -> H2s (overlays Xls) ========
#pragma unroll
    for (int mt = 0; mt < 4; ++mt)
#pragma unroll
      for (int st = 0; st < 2; ++st) acc[mt][st] = vzero;
    {
      const _Float16* wb = W2t + ((size_t)e * H_DIM + hbase + l16) * H_DIM + kq;
      half8 a_p[2][4];
#pragma unroll
      for (int p = 0; p < 2; ++p)
#pragma unroll
        for (int mt = 0; mt < 4; ++mt)
          a_p[p][mt] = *(const half8*)(wb + (size_t)mt * 16 * H_DIM + p * 32);
#pragma unroll
      for (int kb = 0; kb < H_DIM; kb += 32) {
        int p = (kb >> 5) & 1;
        half8 a_cur[4];
#pragma unroll
        for (int mt = 0; mt < 4; ++mt) a_cur[mt] = a_p[p][mt];
        if (kb + 64 < H_DIM) {
#pragma unroll
          for (int mt = 0; mt < 4; ++mt)
            a_p[p][mt] = *(const half8*)(wb + (size_t)mt * 16 * H_DIM + kb + 64);
        }
        half8 b_cur[2];
#pragma unroll
        for (int st = 0; st < 2; ++st)
          b_cur[st] = *(const half8*)&H1s[st * 16 + l16][kb + kq];
#pragma unroll
        for (int mt = 0; mt < 4; ++mt)
#pragma unroll
          for (int st = 0; st < 2; ++st)
            acc[mt][st] = __builtin_amdgcn_mfma_f32_16x16x32_f16(a_cur[mt], b_cur[st], acc[mt][st], 0, 0, 0);
      }
      __syncthreads();  // all waves done reading Xls before the overlay write
#pragma unroll
      for (int mt = 0; mt < 4; ++mt) {
        int h0 = hbase + mt * 16 + quad * 4;
        float4v bb = *(const float4v*)&b2[e * H_DIM + h0];
#pragma unroll
        for (int st = 0; st < 2; ++st) {
          half4 hv;
#pragma unroll
          for (int r = 0; r < 4; ++r) {
            float v = acc[mt][st][r] + bb[r];
            hv[r] = (_Float16)(v > 0.f ? v : 0.f);
          }
          *(half4*)&H2s[st * 16 + l16][h0] = hv;
        }
      }
    }
    __syncthreads();

    // ======== Layer 3: waves 0,1 -> 8 output cols, scatter to out ========
    if (wave < 2) {
      float4v acc3 = vzero;
      const _Float16* wb3 = W3t + ((size_t)e * 16 + l16) * H_DIM + kq;
#pragma unroll
      for (int kb = 0; kb < H_DIM; kb += 32) {
        half8 afrag = *(const half8*)(wb3 + kb);
        half8 bfrag = *(const half8*)&H2s[wave * 16 + l16][kb + kq];
        acc3 = __builtin_amdgcn_mfma_f32_16x16x32_f16(afrag, bfrag, acc3, 0, 0, 0);
      }
      int si = tile0 + wave * 16 + l16;
      if (quad < 2 && si < cnt) {
        int row = idxg[wave * 16 + l16];
        float4v bb = *(const float4v*)&b3[e * OUT_COLS + quad * 4];
        float4v y;
#pragma unroll
        for (int r = 0; r < 4; ++r) y[r] = acc3[r] + bb[r];
        *(float4v*)&out[(size_t)row * DA + quad * 4] = y;
      }
    }
  }
}

extern "C" void kernel_launch(void* const* d_in, const int* in_sizes, int n_in,
                              void* d_out, int out_size, void* d_ws, size_t ws_size,
                              hipStream_t stream) {
  const float* features = (const float*)d_in[0];
  const float* W1 = (const float*)d_in[1];
  const float* b1 = (const float*)d_in[2];
  const float* W2 = (const float*)d_in[3];
  const float* b2 = (const float*)d_in[4];
  const float* W3 = (const float*)d_in[5];
  const float* b3 = (const float*)d_in[6];
  const int* act = (const int*)d_in[7];
  float* out = (float*)d_out;

  char* ws = (char*)d_ws;
  int* counts = (int*)ws;                                      // 256 B
  int* idxbuf = (int*)(ws + 256);                              // 512 KiB
  _Float16* W1t = (_Float16*)(ws + 256 + 524288);              // 2 MiB
  _Float16* W2t = (_Float16*)(ws + 256 + 524288 + 2097152);    // 1 MiB
  _Float16* W3t = (_Float16*)(ws + 256 + 524288 + 2097152 + 1048576);  // 64 KiB

  k_prep<<<64 + 8 * 193, 256, 0, stream>>>(W1, W2, W3, act, W1t, W2t, W3t, idxbuf, counts);
  k_mlp<<<512, 256, 0, stream>>>(features, W1t, W2t, W3t, b1, b2, b3, counts, idxbuf, out);
}